// Round 1
// baseline (885.181 us; speedup 1.0000x reference)
//
#include <hip/hip_runtime.h>

#define DEV __device__ __forceinline__

// ---------- helpers ----------
DEV unsigned short f2bf(float x) {
    unsigned u = __float_as_uint(x);
    unsigned r = (u + 0x7FFFu + ((u >> 16) & 1u)) >> 16;
    return (unsigned short)r;
}
DEV unsigned pack_bf2(float a, float b) {
    return (unsigned)f2bf(a) | ((unsigned)f2bf(b) << 16);
}
DEV float bf2f(unsigned short v) {
    return __uint_as_float(((unsigned)v) << 16);
}
DEV float fastcos(float x) {  // cos(x), x in radians
    float r = x * 0.15915494309189535f;  // -> revolutions
    r = r - floorf(r);                   // [0,1)
    return __builtin_amdgcn_cosf(r);     // v_cos_f32: cos(2*pi*r)
}

// ---------- K0: build transposed weights ----------
__global__ void prep_kernel(const float* __restrict__ W_user, const float* __restrict__ W_item,
                            const float* __restrict__ We_ui, const float* __restrict__ be_ui,
                            const float* __restrict__ We_iu, const float* __restrict__ be_iu,
                            const float* __restrict__ dW1, const float* __restrict__ dW2,
                            float* __restrict__ Wt_user, float* __restrict__ Wt_item,
                            float* __restrict__ Wct, float* __restrict__ bc,
                            float* __restrict__ W1t, float* __restrict__ W2t) {
    int t = threadIdx.x;
    for (int i = t; i < 1024; i += 256) {           // W[k][d] -> Wt[d][k], 32x32
        int k = i / 32, d = i % 32;
        Wt_user[d * 32 + k] = W_user[i];
        Wt_item[d * 32 + k] = W_item[i];
    }
    for (int i = t; i < 4096; i += 256) {           // combined We: Wct[j][k], j<32 ui, j>=32 iu
        int j = i / 64, k = i % 64;
        Wct[i] = (j < 32) ? We_ui[k * 32 + j] : We_iu[k * 32 + (j - 32)];
    }
    for (int i = t; i < 64; i += 256)
        bc[i] = (i < 32) ? be_ui[i] : be_iu[i - 32];
    for (int i = t; i < 4096; i += 256) {           // dec_W1[k][j] -> W1t[j][k], 64x64
        int j = i / 64, k = i % 64;
        W1t[i] = dW1[k * 64 + j];
    }
    for (int i = t; i < 1024; i += 256) {           // dec_W2[j][c] -> W2t[c][j], 16x64
        int c = i / 64, j = i % 64;
        W2t[i] = dW2[j * 16 + c];
    }
}

// ---------- K1: h = mem[ids] @ W  (one thread per row) ----------
__global__ __launch_bounds__(256) void node_linear_kernel(
        const float* __restrict__ mem, const int* __restrict__ ids,
        const float* __restrict__ Wt, float* __restrict__ h, int B) {
    int r = blockIdx.x * 256 + threadIdx.x;
    if (r >= B) return;
    int id = ids[r];
    const float4* m4 = (const float4*)(mem + (size_t)id * 32);
    float m[32];
#pragma unroll
    for (int q = 0; q < 8; ++q) {
        float4 v = m4[q];
        m[4 * q + 0] = v.x; m[4 * q + 1] = v.y; m[4 * q + 2] = v.z; m[4 * q + 3] = v.w;
    }
    float* hr = h + (size_t)r * 32;
    for (int db = 0; db < 8; ++db) {   // 4 outputs per iter
        float acc[4];
#pragma unroll
        for (int u = 0; u < 4; ++u) {
            const float* wr = Wt + (size_t)(db * 4 + u) * 32;
            float a = 0.f;
#pragma unroll
            for (int k = 0; k < 32; ++k) a = fmaf(m[k], wr[k], a);
            acc[u] = a;
        }
        float4 o; o.x = acc[0]; o.y = acc[1]; o.z = acc[2]; o.w = acc[3];
        *(float4*)(hr + db * 4) = o;
    }
}

// ---------- K2: proj[r][0:64] = feat[r] @ Wct + bc  (bf16 out, one thread per row) ----------
__global__ __launch_bounds__(256) void proj_kernel(
        const float* __restrict__ feat, const float* __restrict__ Wct,
        const float* __restrict__ bc, unsigned short* __restrict__ proj, int NE) {
    int r = blockIdx.x * 256 + threadIdx.x;
    if (r >= NE) return;
    const float4* f4 = (const float4*)(feat + (size_t)r * 64);
    float f[64];
#pragma unroll
    for (int q = 0; q < 16; ++q) {
        float4 v = f4[q];
        f[4 * q + 0] = v.x; f[4 * q + 1] = v.y; f[4 * q + 2] = v.z; f[4 * q + 3] = v.w;
    }
    unsigned short* orow = proj + (size_t)r * 64;
    for (int jb = 0; jb < 8; ++jb) {   // 8 outputs per iter
        float acc[8];
#pragma unroll
        for (int u = 0; u < 8; ++u) acc[u] = bc[jb * 8 + u];
#pragma unroll
        for (int u = 0; u < 8; ++u) {
            const float* wr = Wct + (size_t)(jb * 8 + u) * 64;
#pragma unroll
            for (int k = 0; k < 64; ++k) acc[u] = fmaf(f[k], wr[k], acc[u]);
        }
        uint4 p;
        p.x = pack_bf2(acc[0], acc[1]);
        p.y = pack_bf2(acc[2], acc[3]);
        p.z = pack_bf2(acc[4], acc[5]);
        p.w = pack_bf2(acc[6], acc[7]);
        *(uint4*)(orow + jb * 8) = p;
    }
}

// ---------- K3: per-edge message + scatter-add (32 lanes per edge, one per d) ----------
__global__ __launch_bounds__(256) void edge_kernel(
        const int* __restrict__ src, const int* __restrict__ dst,
        const int* __restrict__ eidx, const float* __restrict__ rt,
        const float* __restrict__ h, const unsigned short* __restrict__ proj,
        float* __restrict__ agg,
        const float* __restrict__ tw, const float* __restrict__ tb, int E) {
    long long i = (long long)blockIdx.x * 256 + threadIdx.x;
    int e = (int)(i >> 5), d = (int)(i & 31);
    if (e >= E) return;
    int s = src[e], dd = dst[e], ix = eidx[e];
    float t = rt[e];
    float c = fastcos(fmaf(t, tw[d], tb[d]));
    float pv = bf2f(proj[(size_t)ix * 64 + d]);
    float m = h[(size_t)s * 32 + d] + pv + c;
    unsafeAtomicAdd(&agg[(size_t)dd * 32 + d], m);
}

// ---------- K4: relu + decoder MLP (one thread per row) ----------
__global__ __launch_bounds__(256) void decoder_kernel(
        const float* __restrict__ h_user, const float* __restrict__ h_item,
        const float* __restrict__ agg_user, const float* __restrict__ agg_item,
        const float* __restrict__ W1t, const float* __restrict__ b1,
        const float* __restrict__ W2t, const float* __restrict__ b2,
        const float* __restrict__ W3, const float* __restrict__ b3,
        float* __restrict__ out, int B) {
    int i = blockIdx.x * 256 + threadIdx.x;
    if (i >= B) return;
    float z[64];
    {
        const float4* a4 = (const float4*)(h_user + (size_t)i * 32);
        const float4* b4 = (const float4*)(agg_user + (size_t)i * 32);
#pragma unroll
        for (int q = 0; q < 8; ++q) {
            float4 a = a4[q], b = b4[q];
            z[4 * q + 0] = fmaxf(a.x + b.x, 0.f);
            z[4 * q + 1] = fmaxf(a.y + b.y, 0.f);
            z[4 * q + 2] = fmaxf(a.z + b.z, 0.f);
            z[4 * q + 3] = fmaxf(a.w + b.w, 0.f);
        }
    }
    {
        const float4* a4 = (const float4*)(h_item + (size_t)i * 32);
        const float4* b4 = (const float4*)(agg_item + (size_t)i * 32);
#pragma unroll
        for (int q = 0; q < 8; ++q) {
            float4 a = a4[q], b = b4[q];
            z[32 + 4 * q + 0] = fmaxf(a.x + b.x, 0.f);
            z[32 + 4 * q + 1] = fmaxf(a.y + b.y, 0.f);
            z[32 + 4 * q + 2] = fmaxf(a.z + b.z, 0.f);
            z[32 + 4 * q + 3] = fmaxf(a.w + b.w, 0.f);
        }
    }
    float x2[16];
#pragma unroll
    for (int c = 0; c < 16; ++c) x2[c] = b2[c];
    for (int jb = 0; jb < 8; ++jb) {   // 8 hidden units of layer-1 per iter, folded into x2
        float a[8];
#pragma unroll
        for (int u = 0; u < 8; ++u) {
            int j = jb * 8 + u;
            const float* wr = W1t + (size_t)j * 64;
            float acc = b1[j];
#pragma unroll
            for (int k = 0; k < 64; ++k) acc = fmaf(z[k], wr[k], acc);
            a[u] = fmaxf(acc, 0.f);
        }
#pragma unroll
        for (int c = 0; c < 16; ++c) {
            const float* w2r = W2t + (size_t)c * 64 + jb * 8;
            float acc = x2[c];
#pragma unroll
            for (int u = 0; u < 8; ++u) acc = fmaf(a[u], w2r[u], acc);
            x2[c] = acc;
        }
    }
    float o = b3[0];
#pragma unroll
    for (int c = 0; c < 16; ++c) o = fmaf(fmaxf(x2[c], 0.f), W3[c], o);
    out[i] = o;
}

extern "C" void kernel_launch(void* const* d_in, const int* in_sizes, int n_in,
                              void* d_out, int out_size, void* d_ws, size_t ws_size,
                              hipStream_t stream) {
    const float* mem_user = (const float*)d_in[0];
    const float* mem_item = (const float*)d_in[1];
    const int*   ids_user = (const int*)d_in[2];
    const int*   ids_item = (const int*)d_in[3];
    const int*   src_ui   = (const int*)d_in[4];
    const int*   dst_ui   = (const int*)d_in[5];
    const int*   src_iu   = (const int*)d_in[6];
    const int*   dst_iu   = (const int*)d_in[7];
    const int*   eidx_ui  = (const int*)d_in[8];
    const int*   eidx_iu  = (const int*)d_in[9];
    const float* rt_ui    = (const float*)d_in[10];
    const float* rt_iu    = (const float*)d_in[11];
    const float* feat     = (const float*)d_in[12];
    const float* W_user   = (const float*)d_in[13];
    const float* W_item   = (const float*)d_in[14];
    const float* We_ui    = (const float*)d_in[15];
    const float* be_ui    = (const float*)d_in[16];
    const float* We_iu    = (const float*)d_in[17];
    const float* be_iu    = (const float*)d_in[18];
    const float* tw       = (const float*)d_in[19];
    const float* tb       = (const float*)d_in[20];
    const float* dW1      = (const float*)d_in[21];
    const float* db1      = (const float*)d_in[22];
    const float* dW2      = (const float*)d_in[23];
    const float* db2      = (const float*)d_in[24];
    const float* dW3      = (const float*)d_in[25];
    const float* db3      = (const float*)d_in[26];

    const int B  = in_sizes[2];
    const int E  = in_sizes[4];
    const int NE = in_sizes[12] / 64;

    float* w = (float*)d_ws;
    const size_t hsz = (size_t)B * 32;
    float* h_user   = w;
    float* h_item   = h_user + hsz;
    float* agg_user = h_item + hsz;
    float* agg_item = agg_user + hsz;
    float* Wt_user  = agg_item + hsz;
    float* Wt_item  = Wt_user + 1024;
    float* Wct      = Wt_item + 1024;
    float* bc       = Wct + 4096;
    float* W1t      = bc + 64;
    float* W2t      = W1t + 4096;
    unsigned short* proj = (unsigned short*)(W2t + 1024);  // [NE][64] bf16

    prep_kernel<<<1, 256, 0, stream>>>(W_user, W_item, We_ui, be_ui, We_iu, be_iu, dW1, dW2,
                                       Wt_user, Wt_item, Wct, bc, W1t, W2t);
    node_linear_kernel<<<(B + 255) / 256, 256, 0, stream>>>(mem_user, ids_user, Wt_user, h_user, B);
    node_linear_kernel<<<(B + 255) / 256, 256, 0, stream>>>(mem_item, ids_item, Wt_item, h_item, B);
    hipMemsetAsync(agg_user, 0, 2 * hsz * sizeof(float), stream);  // agg_user+agg_item contiguous
    proj_kernel<<<(NE + 255) / 256, 256, 0, stream>>>(feat, Wct, bc, proj, NE);

    long long tot = (long long)E * 32;
    int eblocks = (int)((tot + 255) / 256);
    edge_kernel<<<eblocks, 256, 0, stream>>>(src_ui, dst_ui, eidx_ui, rt_ui,
                                             h_user, proj + 0, agg_item, tw, tb, E);
    edge_kernel<<<eblocks, 256, 0, stream>>>(src_iu, dst_iu, eidx_iu, rt_iu,
                                             h_item, proj + 32, agg_user, tw, tb, E);
    decoder_kernel<<<(B + 255) / 256, 256, 0, stream>>>(h_user, h_item, agg_user, agg_item,
                                                        W1t, db1, W2t, db2, dW3, db3,
                                                        (float*)d_out, B);
}

// Round 2
// 801.035 us; speedup vs baseline: 1.1050x; 1.1050x over previous
//
#include <hip/hip_runtime.h>

#define DEV __device__ __forceinline__

typedef __attribute__((ext_vector_type(8))) short short8;    // 8 bf16 (4 VGPRs)
typedef __attribute__((ext_vector_type(16))) float float16;  // MFMA 32x32 accumulator

// ---------- helpers ----------
DEV unsigned short f2bf(float x) {
    unsigned u = __float_as_uint(x);
    unsigned r = (u + 0x7FFFu + ((u >> 16) & 1u)) >> 16;
    return (unsigned short)r;
}
DEV unsigned pack_bf2(float a, float b) {
    return (unsigned)f2bf(a) | ((unsigned)f2bf(b) << 16);
}
DEV float bf2f(unsigned short v) {
    return __uint_as_float(((unsigned)v) << 16);
}
DEV float fastcos(float x) {  // cos(x), x in radians
    float r = x * 0.15915494309189535f;  // -> revolutions
    r = r - floorf(r);                   // [0,1)
    return __builtin_amdgcn_cosf(r);     // v_cos_f32: cos(2*pi*r)
}

// ---------- K0: build transposed / fragment-packed weights ----------
// Wb: B-fragments for v_mfma_f32_32x32x16_bf16, combined We_ui(cols 0..31)+We_iu(cols 32..63).
// Fragment layout: lane l holds col n=l&31, k=(l>>5)*8+i (i=0..7); frag index = t*2+n2
// (t = k-tile of 16, n2 = col-tile of 32). Flat: Wb[((t*2+n2)*64 + l)*8 + i].
__global__ void prep_kernel(const float* __restrict__ W_user, const float* __restrict__ W_item,
                            const float* __restrict__ We_ui, const float* __restrict__ be_ui,
                            const float* __restrict__ We_iu, const float* __restrict__ be_iu,
                            const float* __restrict__ dW1, const float* __restrict__ dW2,
                            float* __restrict__ Wt_user, float* __restrict__ Wt_item,
                            unsigned short* __restrict__ Wb, float* __restrict__ bc,
                            float* __restrict__ W1t, float* __restrict__ W2t) {
    int t = threadIdx.x;
    for (int i = t; i < 1024; i += 256) {           // W[k][d] -> Wt[d][k], 32x32
        int k = i / 32, d = i % 32;
        Wt_user[d * 32 + k] = W_user[i];
        Wt_item[d * 32 + k] = W_item[i];
    }
    for (int i = t; i < 4096; i += 256) {           // MFMA B fragments (bf16)
        int kt   = i >> 10;          // k-tile 0..3
        int rem  = i & 1023;
        int n2   = rem >> 9;         // col-tile 0..1
        int rem2 = rem & 511;
        int l    = rem2 >> 3;        // lane 0..63
        int ii   = rem2 & 7;         // elem 0..7
        int k = kt * 16 + (l >> 5) * 8 + ii;
        int n = (l & 31);
        float v = n2 ? We_iu[k * 32 + n] : We_ui[k * 32 + n];
        Wb[i] = f2bf(v);
    }
    for (int i = t; i < 64; i += 256)
        bc[i] = (i < 32) ? be_ui[i] : be_iu[i - 32];
    for (int i = t; i < 4096; i += 256) {           // dec_W1[k][j] -> W1t[j][k], 64x64
        int j = i / 64, k = i % 64;
        W1t[i] = dW1[k * 64 + j];
    }
    for (int i = t; i < 1024; i += 256) {           // dec_W2[j][c] -> W2t[c][j], 16x64
        int c = i / 64, j = i % 64;
        W2t[i] = dW2[j * 16 + c];
    }
}

// ---------- K1: h = mem[ids] @ W  (one thread per row) ----------
__global__ __launch_bounds__(256) void node_linear_kernel(
        const float* __restrict__ mem, const int* __restrict__ ids,
        const float* __restrict__ Wt, float* __restrict__ h, int B) {
    int r = blockIdx.x * 256 + threadIdx.x;
    if (r >= B) return;
    int id = ids[r];
    const float4* m4 = (const float4*)(mem + (size_t)id * 32);
    float m[32];
#pragma unroll
    for (int q = 0; q < 8; ++q) {
        float4 v = m4[q];
        m[4 * q + 0] = v.x; m[4 * q + 1] = v.y; m[4 * q + 2] = v.z; m[4 * q + 3] = v.w;
    }
    float* hr = h + (size_t)r * 32;
    for (int db = 0; db < 8; ++db) {   // 4 outputs per iter
        float acc[4];
#pragma unroll
        for (int u = 0; u < 4; ++u) {
            const float* wr = Wt + (size_t)(db * 4 + u) * 32;
            float a = 0.f;
#pragma unroll
            for (int k = 0; k < 32; ++k) a = fmaf(m[k], wr[k], a);
            acc[u] = a;
        }
        float4 o; o.x = acc[0]; o.y = acc[1]; o.z = acc[2]; o.w = acc[3];
        *(float4*)(hr + db * 4) = o;
    }
}

// ---------- K2: proj = feat @ [We_ui|We_iu] + bias, bf16 out — MFMA version ----------
// Block = 256 threads = 4 waves; each wave does 32 rows x 64 cols via 8x
// v_mfma_f32_32x32x16_bf16 (4 K-tiles x 2 N-tiles). C-layout scatter is
// reorganized through LDS (row stride 72 shorts -> <=2-way banks = free),
// then stored as full 128B lines back-to-back.
__global__ __launch_bounds__(256) void proj_mfma_kernel(
        const float* __restrict__ feat, const unsigned short* __restrict__ Wb,
        const float* __restrict__ bc, unsigned short* __restrict__ proj, int NE) {
    __shared__ unsigned short lds[128 * 72];
    const int lane = threadIdx.x & 63;
    const int wave = threadIdx.x >> 6;
    const int col  = lane & 31;
    const int half = lane >> 5;

    // B fragments (weights): 8 x 16B per lane, loaded once
    short8 bfrag[8];
    const short8* wb8 = (const short8*)Wb;
#pragma unroll
    for (int f = 0; f < 8; ++f) bfrag[f] = wb8[f * 64 + lane];

    // A fragments: this lane's row, fp32 -> bf16
    int r = blockIdx.x * 128 + wave * 32 + col;
    if (r >= NE) r = NE - 1;  // clamp; stores are guarded below
    const float* fr = feat + (size_t)r * 64 + half * 8;
    short8 afrag[4];
#pragma unroll
    for (int t = 0; t < 4; ++t) {
        float4 a = *(const float4*)(fr + t * 16);
        float4 b = *(const float4*)(fr + t * 16 + 4);
        short8 s;
        s[0] = (short)f2bf(a.x); s[1] = (short)f2bf(a.y);
        s[2] = (short)f2bf(a.z); s[3] = (short)f2bf(a.w);
        s[4] = (short)f2bf(b.x); s[5] = (short)f2bf(b.y);
        s[6] = (short)f2bf(b.z); s[7] = (short)f2bf(b.w);
        afrag[t] = s;
    }

    float16 acc0, acc1;
    float b0 = bc[col], b1 = bc[32 + col];
#pragma unroll
    for (int i = 0; i < 16; ++i) { acc0[i] = b0; acc1[i] = b1; }
#pragma unroll
    for (int t = 0; t < 4; ++t) {
        acc0 = __builtin_amdgcn_mfma_f32_32x32x16_bf16(afrag[t], bfrag[t * 2 + 0], acc0, 0, 0, 0);
        acc1 = __builtin_amdgcn_mfma_f32_32x32x16_bf16(afrag[t], bfrag[t * 2 + 1], acc1, 0, 0, 0);
    }

    // C/D layout: col = lane&31, row = (reg&3) + 8*(reg>>2) + 4*(lane>>5)
#pragma unroll
    for (int reg = 0; reg < 16; ++reg) {
        int rl = wave * 32 + (reg & 3) + 8 * (reg >> 2) + 4 * half;
        lds[rl * 72 + col]      = f2bf(acc0[reg]);
        lds[rl * 72 + 32 + col] = f2bf(acc1[reg]);
    }
    __syncthreads();

    // Store: thread -> (row = tid>>1, 64B half-row), full-line writes
    int trow = threadIdx.x >> 1, thalf = threadIdx.x & 1;
    int grow = blockIdx.x * 128 + trow;
    if (grow < NE) {
        const uint4* lsrc = (const uint4*)(lds + trow * 72 + thalf * 32);
        uint4* gdst = (uint4*)(proj + (size_t)grow * 64 + thalf * 32);
#pragma unroll
        for (int s = 0; s < 4; ++s) gdst[s] = lsrc[s];
    }
}

// ---------- K3: per-edge message + scatter-add (32 lanes per edge, one per d) ----------
__global__ __launch_bounds__(256) void edge_kernel(
        const int* __restrict__ src, const int* __restrict__ dst,
        const int* __restrict__ eidx, const float* __restrict__ rt,
        const float* __restrict__ h, const unsigned short* __restrict__ proj,
        float* __restrict__ agg,
        const float* __restrict__ tw, const float* __restrict__ tb, int E) {
    long long i = (long long)blockIdx.x * 256 + threadIdx.x;
    int e = (int)(i >> 5), d = (int)(i & 31);
    if (e >= E) return;
    int s = src[e], dd = dst[e], ix = eidx[e];
    float t = rt[e];
    float c = fastcos(fmaf(t, tw[d], tb[d]));
    float pv = bf2f(proj[(size_t)ix * 64 + d]);
    float m = h[(size_t)s * 32 + d] + pv + c;
    unsafeAtomicAdd(&agg[(size_t)dd * 32 + d], m);
}

// ---------- K4: relu + decoder MLP (one thread per row) ----------
__global__ __launch_bounds__(256) void decoder_kernel(
        const float* __restrict__ h_user, const float* __restrict__ h_item,
        const float* __restrict__ agg_user, const float* __restrict__ agg_item,
        const float* __restrict__ W1t, const float* __restrict__ b1,
        const float* __restrict__ W2t, const float* __restrict__ b2,
        const float* __restrict__ W3, const float* __restrict__ b3,
        float* __restrict__ out, int B) {
    int i = blockIdx.x * 256 + threadIdx.x;
    if (i >= B) return;
    float z[64];
    {
        const float4* a4 = (const float4*)(h_user + (size_t)i * 32);
        const float4* b4 = (const float4*)(agg_user + (size_t)i * 32);
#pragma unroll
        for (int q = 0; q < 8; ++q) {
            float4 a = a4[q], b = b4[q];
            z[4 * q + 0] = fmaxf(a.x + b.x, 0.f);
            z[4 * q + 1] = fmaxf(a.y + b.y, 0.f);
            z[4 * q + 2] = fmaxf(a.z + b.z, 0.f);
            z[4 * q + 3] = fmaxf(a.w + b.w, 0.f);
        }
    }
    {
        const float4* a4 = (const float4*)(h_item + (size_t)i * 32);
        const float4* b4 = (const float4*)(agg_item + (size_t)i * 32);
#pragma unroll
        for (int q = 0; q < 8; ++q) {
            float4 a = a4[q], b = b4[q];
            z[32 + 4 * q + 0] = fmaxf(a.x + b.x, 0.f);
            z[32 + 4 * q + 1] = fmaxf(a.y + b.y, 0.f);
            z[32 + 4 * q + 2] = fmaxf(a.z + b.z, 0.f);
            z[32 + 4 * q + 3] = fmaxf(a.w + b.w, 0.f);
        }
    }
    float x2[16];
#pragma unroll
    for (int c = 0; c < 16; ++c) x2[c] = b2[c];
    for (int jb = 0; jb < 8; ++jb) {   // 8 hidden units of layer-1 per iter, folded into x2
        float a[8];
#pragma unroll
        for (int u = 0; u < 8; ++u) {
            int j = jb * 8 + u;
            const float* wr = W1t + (size_t)j * 64;
            float acc = b1[j];
#pragma unroll
            for (int k = 0; k < 64; ++k) acc = fmaf(z[k], wr[k], acc);
            a[u] = fmaxf(acc, 0.f);
        }
#pragma unroll
        for (int c = 0; c < 16; ++c) {
            const float* w2r = W2t + (size_t)c * 64 + jb * 8;
            float acc = x2[c];
#pragma unroll
            for (int u = 0; u < 8; ++u) acc = fmaf(a[u], w2r[u], acc);
            x2[c] = acc;
        }
    }
    float o = b3[0];
#pragma unroll
    for (int c = 0; c < 16; ++c) o = fmaf(fmaxf(x2[c], 0.f), W3[c], o);
    out[i] = o;
}

extern "C" void kernel_launch(void* const* d_in, const int* in_sizes, int n_in,
                              void* d_out, int out_size, void* d_ws, size_t ws_size,
                              hipStream_t stream) {
    const float* mem_user = (const float*)d_in[0];
    const float* mem_item = (const float*)d_in[1];
    const int*   ids_user = (const int*)d_in[2];
    const int*   ids_item = (const int*)d_in[3];
    const int*   src_ui   = (const int*)d_in[4];
    const int*   dst_ui   = (const int*)d_in[5];
    const int*   src_iu   = (const int*)d_in[6];
    const int*   dst_iu   = (const int*)d_in[7];
    const int*   eidx_ui  = (const int*)d_in[8];
    const int*   eidx_iu  = (const int*)d_in[9];
    const float* rt_ui    = (const float*)d_in[10];
    const float* rt_iu    = (const float*)d_in[11];
    const float* feat     = (const float*)d_in[12];
    const float* W_user   = (const float*)d_in[13];
    const float* W_item   = (const float*)d_in[14];
    const float* We_ui    = (const float*)d_in[15];
    const float* be_ui    = (const float*)d_in[16];
    const float* We_iu    = (const float*)d_in[17];
    const float* be_iu    = (const float*)d_in[18];
    const float* tw       = (const float*)d_in[19];
    const float* tb       = (const float*)d_in[20];
    const float* dW1      = (const float*)d_in[21];
    const float* db1      = (const float*)d_in[22];
    const float* dW2      = (const float*)d_in[23];
    const float* db2      = (const float*)d_in[24];
    const float* dW3      = (const float*)d_in[25];
    const float* db3      = (const float*)d_in[26];

    const int B  = in_sizes[2];
    const int E  = in_sizes[4];
    const int NE = in_sizes[12] / 64;

    float* w = (float*)d_ws;
    const size_t hsz = (size_t)B * 32;
    float* h_user   = w;
    float* h_item   = h_user + hsz;
    float* agg_user = h_item + hsz;
    float* agg_item = agg_user + hsz;
    float* Wt_user  = agg_item + hsz;
    float* Wt_item  = Wt_user + 1024;
    unsigned short* Wb = (unsigned short*)(Wt_item + 1024);  // 4096 bf16 = 2048 floats
    float* bc       = (float*)(Wb + 4096);
    float* W1t      = bc + 64;
    float* W2t      = W1t + 4096;
    unsigned short* proj = (unsigned short*)(W2t + 1024);  // [NE][64] bf16

    prep_kernel<<<1, 256, 0, stream>>>(W_user, W_item, We_ui, be_ui, We_iu, be_iu, dW1, dW2,
                                       Wt_user, Wt_item, Wb, bc, W1t, W2t);
    node_linear_kernel<<<(B + 255) / 256, 256, 0, stream>>>(mem_user, ids_user, Wt_user, h_user, B);
    node_linear_kernel<<<(B + 255) / 256, 256, 0, stream>>>(mem_item, ids_item, Wt_item, h_item, B);
    hipMemsetAsync(agg_user, 0, 2 * hsz * sizeof(float), stream);  // agg_user+agg_item contiguous
    proj_mfma_kernel<<<(NE + 127) / 128, 256, 0, stream>>>(feat, Wb, bc, proj, NE);

    long long tot = (long long)E * 32;
    int eblocks = (int)((tot + 255) / 256);
    edge_kernel<<<eblocks, 256, 0, stream>>>(src_ui, dst_ui, eidx_ui, rt_ui,
                                             h_user, proj + 0, agg_item, tw, tb, E);
    edge_kernel<<<eblocks, 256, 0, stream>>>(src_iu, dst_iu, eidx_iu, rt_iu,
                                             h_item, proj + 32, agg_user, tw, tb, E);
    decoder_kernel<<<(B + 255) / 256, 256, 0, stream>>>(h_user, h_item, agg_user, agg_item,
                                                        W1t, db1, W2t, db2, dW3, db3,
                                                        (float*)d_out, B);
}